// Round 3
// baseline (563.445 us; speedup 1.0000x reference)
//
#include <hip/hip_runtime.h>
#include <stdint.h>

#define BATCH 512
#define FEAT 512
#define NCLS 100000
#define BM 128
#define BN 128
#define BK 64
#define NBLK_N 782            // ceil(100000/128)
#define NBLK (NBLK_N * 4)     // 3128 total blocks, divisible by 8 (XCD count)
#define NCHUNK (NBLK_N * 2)   // per-row softmax partial chunks (one per 64-col wave tile)
#define SCALE_S 32.0f
#define MARGIN 0.5f
#define MM_CONST 0.23971276930210156f  // 0.5*sin(pi-0.5)
#define PI_F 3.14159265358979f

typedef unsigned int u32;
typedef unsigned short u16;
typedef __bf16 bf16x8 __attribute__((ext_vector_type(8)));
typedef float f32x4 __attribute__((ext_vector_type(4)));

__device__ __forceinline__ u16 f2bf(float f) {
  u32 u = __float_as_uint(f);
  u += 0x7fffu + ((u >> 16) & 1u);
  return (u16)(u >> 16);
}

__device__ __forceinline__ void async_copy16(const void* g, void* l) {
  __builtin_amdgcn_global_load_lds((const __attribute__((address_space(1))) u32*)g,
                                   (__attribute__((address_space(3))) u32*)l,
                                   16, 0, 0);
}

__device__ __forceinline__ float block_reduce_sum(float v, float* sbuf) {
  for (int off = 1; off < 64; off <<= 1) v += __shfl_xor(v, off, 64);
  int wid = threadIdx.x >> 6, lane = threadIdx.x & 63;
  __syncthreads();
  if (lane == 0) sbuf[wid] = v;
  __syncthreads();
  return sbuf[0] + sbuf[1] + sbuf[2] + sbuf[3];
}

// Fused L2-normalize of inputs (BATCH rows) and weight (NCLS rows), f32 -> bf16.
// One wave per row, grid-stride; no LDS, no barriers; float4 loads, ushort4 stores.
// Also zeroes out[0] (loss accumulator used by combine_kernel's atomicAdd).
__global__ __launch_bounds__(256) void norm_all_kernel(const float* __restrict__ inputs,
                                                       const float* __restrict__ weight,
                                                       u16* __restrict__ dstA,
                                                       u16* __restrict__ dstB,
                                                       float* __restrict__ out0) {
  if (blockIdx.x == 0 && threadIdx.x == 0) out0[0] = 0.0f;
  const int lane = threadIdx.x & 63;
  const int gw = (blockIdx.x * 256 + threadIdx.x) >> 6;  // global wave id
  const int nw = gridDim.x * 4;                          // total waves
  for (int row = gw; row < BATCH + NCLS; row += nw) {
    const float* src;
    u16* dst;
    if (row < BATCH) {
      src = inputs + (size_t)row * FEAT;
      dst = dstA + (size_t)row * FEAT;
    } else {
      src = weight + (size_t)(row - BATCH) * FEAT;
      dst = dstB + (size_t)(row - BATCH) * FEAT;
    }
    const float4* p4 = (const float4*)src;
    float4 a = p4[lane];        // elements 4*lane .. 4*lane+3
    float4 b = p4[lane + 64];   // elements 256+4*lane ..
    float ss = a.x * a.x + a.y * a.y + a.z * a.z + a.w * a.w +
               b.x * b.x + b.y * b.y + b.z * b.z + b.w * b.w;
#pragma unroll
    for (int off = 1; off < 64; off <<= 1) ss += __shfl_xor(ss, off, 64);
    float inv = 1.0f / fmaxf(sqrtf(ss), 1e-12f);
    ushort4 oa, ob;
    oa.x = f2bf(a.x * inv); oa.y = f2bf(a.y * inv);
    oa.z = f2bf(a.z * inv); oa.w = f2bf(a.w * inv);
    ob.x = f2bf(b.x * inv); ob.y = f2bf(b.y * inv);
    ob.z = f2bf(b.z * inv); ob.w = f2bf(b.w * inv);
    ((ushort4*)dst)[lane] = oa;
    ((ushort4*)dst)[lane + 64] = ob;
  }
}

// C[512 x 100000] = Ahat @ Bhat^T (bf16 MFMA), fused clip/margin/scale epilogue,
// writes outs (nontemporal) and per-(row, 64-col-chunk) softmax partial sums
// with FIXED max = S (logits are analytically <= S): partial = sum exp(v - S).
// v3 structure (T3/T4 deep pipeline):
//  - A fragments register-double-buffered, loaded 1 tile ahead direct from
//    global (A is 512 KB, L2-hot everywhere).
//  - B triple-buffered in LDS, staged 2 tiles ahead via global_load_lds;
//    steady state keeps 28 VMEM ops in flight, counted vmcnt(16) retires
//    exactly the current tile (== compiler's own wait for the A-regs).
//  - manual 8-step unroll, distinct __shared__ objects, compile-time buffer
//    names so alias analysis never forces a vmcnt(0) drain.
__global__ __launch_bounds__(256, 3) void gemm_kernel(const u16* __restrict__ A,
                                                      const u16* __restrict__ B,
                                                      const int* __restrict__ labels,
                                                      float* __restrict__ outs,
                                                      float* __restrict__ partials) {
  __shared__ __align__(16) u16 sB0[BN * BK];
  __shared__ __align__(16) u16 sB1[BN * BK];
  __shared__ __align__(16) u16 sB2[BN * BK];
  __shared__ int sLab[BM];

  const int tid = threadIdx.x;
  const int lane = tid & 63;
  const int wid = tid >> 6;
  const int waveM = wid >> 1, waveN = wid & 1;
  // bijective XCD swizzle: NBLK % 8 == 0; XCD x processes logical ids
  // [x*NBLK/8, (x+1)*NBLK/8); logical order is m-fastest so the 4 B-tile
  // sharers are temporally adjacent on one XCD.
  const int orig = blockIdx.x;
  const int L = (orig & 7) * (NBLK / 8) + (orig >> 3);
  const int bm = L & 3, bn = L >> 2;
  const int quad = lane >> 4, l15 = lane & 15;

  if (tid < BM) sLab[tid] = labels[bm * BM + tid];

  // B staging map: LDS 16B-block index idx16 holds global
  // (row = idx16>>3, colblock = (idx16&7)^(row&7))
  const u16* gB[4];
#pragma unroll
  for (int rd = 0; rd < 4; ++rd) {
    int idx = rd * 256 + tid;
    int r = idx >> 3;
    int cb = (idx & 7) ^ (r & 7);
    int brow = bn * BN + r;
    if (brow >= NCLS) brow = NCLS - 1;  // clamp; masked in epilogue
    gB[rd] = B + (size_t)brow * FEAT + cb * 8;
  }
  // A fragment base: row (within tile) = waveM*64 + mi*16 + l15
  const u16* gA = A + (size_t)(bm * BM + waveM * 64 + l15) * FEAT;

  f32x4 acc[4][4] = {};
  bf16x8 a0[4][2], a1[4][2];

#define STAGE_B(SBUF, KT)                                                   \
  do {                                                                      \
    _Pragma("unroll") for (int rd = 0; rd < 4; ++rd)                        \
        async_copy16(gB[rd] + (KT)*BK, &(SBUF)[(rd * 256 + tid) * 8]);      \
  } while (0)

#define LOAD_A(AREG, KT)                                                    \
  do {                                                                      \
    _Pragma("unroll") for (int mi = 0; mi < 4; ++mi)                        \
        _Pragma("unroll") for (int ks = 0; ks < 2; ++ks)                    \
            AREG[mi][ks] = *(const bf16x8*)(gA + (size_t)mi * 16 * FEAT +   \
                                            (KT)*BK + (ks * 4 + quad) * 8); \
  } while (0)

#define COMPUTE(SBUF, AREG)                                                 \
  do {                                                                      \
    _Pragma("unroll") for (int ks = 0; ks < 2; ++ks) {                      \
      int j0 = ks * 4 + quad;                                               \
      bf16x8 bF[4];                                                         \
      _Pragma("unroll") for (int ni = 0; ni < 4; ++ni) {                    \
        int r = waveN * 64 + ni * 16 + l15;                                 \
        bF[ni] = *(const bf16x8*)&(SBUF)[(r * 8 + (j0 ^ (r & 7))) * 8];     \
      }                                                                     \
      _Pragma("unroll") for (int mi = 0; mi < 4; ++mi)                      \
          _Pragma("unroll") for (int ni = 0; ni < 4; ++ni)                  \
              acc[mi][ni] = __builtin_amdgcn_mfma_f32_16x16x32_bf16(        \
                  AREG[mi][ks], bF[ni], acc[mi][ni], 0, 0, 0);              \
    }                                                                       \
  } while (0)

#define SCHED0 __builtin_amdgcn_sched_barrier(0)
#define VMCNT(N) asm volatile("s_waitcnt vmcnt(" #N ")" ::: "memory")
#define BAR asm volatile("s_barrier" ::: "memory")

  // prologue: B tiles 0,1 in flight; A tile 0 in regs; drain everything once.
  STAGE_B(sB0, 0);
  STAGE_B(sB1, 1);
  LOAD_A(a0, 0);
  __syncthreads();  // vmcnt(0)+lgkmcnt(0)+barrier: sB0,sB1,a0,sLab all ready

  // t=0: issue A(1), B(2); everything needed already drained.
  LOAD_A(a1, 1); SCHED0; STAGE_B(sB2, 2); SCHED0;
  COMPUTE(sB0, a0);
  BAR;  // all waves done reading sB0 before t=1 stages B(3) into it
  // t=1: queue [A1:8, B2:4, A2:8, B3:4] -> retire A1 -> 16. sB1 drained at prologue.
  LOAD_A(a0, 2); SCHED0; STAGE_B(sB0, 3); SCHED0;
  VMCNT(16);
  COMPUTE(sB1, a1);
  BAR;
  // t=2: queue [B2:4, A2:8, B3:4, A3:8, B4:4] -> retire B2+A2 -> 16.
  LOAD_A(a1, 3); SCHED0; STAGE_B(sB1, 4); SCHED0;
  VMCNT(16); BAR;  // all waves' B(2) DMA landed
  COMPUTE(sB2, a0);
  BAR;
  // t=3
  LOAD_A(a0, 4); SCHED0; STAGE_B(sB2, 5); SCHED0;
  VMCNT(16); BAR;
  COMPUTE(sB0, a1);
  BAR;
  // t=4
  LOAD_A(a1, 5); SCHED0; STAGE_B(sB0, 6); SCHED0;
  VMCNT(16); BAR;
  COMPUTE(sB1, a0);
  BAR;
  // t=5
  LOAD_A(a0, 6); SCHED0; STAGE_B(sB1, 7); SCHED0;
  VMCNT(16); BAR;
  COMPUTE(sB2, a1);
  BAR;
  // t=6: no more B tiles; queue [B6:4, A6:8, B7:4, A7:8] -> retire B6+A6 -> 12.
  LOAD_A(a1, 7); SCHED0;
  VMCNT(12); BAR;
  COMPUTE(sB0, a0);
  BAR;
  // t=7: drain.
  VMCNT(0); BAR;
  COMPUTE(sB1, a1);

#undef STAGE_B
#undef LOAD_A
#undef COMPUTE

  // epilogue: clip, margin at label col, scale, nontemporal store, partial
  // exp-sums with FIXED max = SCALE_S (logits analytically <= S).
#pragma unroll
  for (int mi = 0; mi < 4; ++mi) {
#pragma unroll
    for (int reg = 0; reg < 4; ++reg) {
      int rloc = waveM * 64 + mi * 16 + quad * 4 + reg;
      int rg = bm * BM + rloc;
      int lab = sLab[rloc];
      float rsum = 0.f;
#pragma unroll
      for (int ni = 0; ni < 4; ++ni) {
        int cg = bn * BN + waveN * 64 + ni * 16 + l15;
        float v = acc[mi][ni][reg];
        v = fminf(fmaxf(v, -1.0f + 1e-6f), 1.0f - 1e-6f);
        if (cg == lab) {  // cos(arccos(x))==x elsewhere; only label col needs transcendentals
          float th = acosf(v) + MARGIN;
          v = (th < PI_F) ? cosf(th) : (v - MM_CONST);
        }
        v *= SCALE_S;
        if (cg < NCLS) {
          __builtin_nontemporal_store(v, &outs[(size_t)rg * NCLS + cg]);
          rsum += __expf(v - SCALE_S);
        }
      }
#pragma unroll
      for (int off = 1; off < 16; off <<= 1) rsum += __shfl_xor(rsum, off, 64);
      if (l15 == 0) partials[(size_t)rg * NCHUNK + (bn * 2 + waveN)] = rsum;
    }
  }
}

// per-row r: (a) sum NCHUNK partial exp-sums -> lse = S + log(sum), accumulate
// mean loss into out[0] via atomicAdd; (b) exact f32 recompute of
// target_cos_in / target_theta_in / target_cos_out.
__global__ __launch_bounds__(256) void combine_kernel(const float* __restrict__ partials,
                                                      const float* __restrict__ outs,
                                                      const int* __restrict__ labels,
                                                      const float* __restrict__ inputs,
                                                      const float* __restrict__ weight,
                                                      float* __restrict__ out0,
                                                      float* __restrict__ tdst) {
  __shared__ float sbuf[4];
  int r = blockIdx.x, tid = threadIdx.x;
  int lab = labels[r];

  // targets: three dot/norm reductions over the full 512-dim row (f32 exact)
  const float2* px = (const float2*)(inputs + (size_t)r * FEAT);
  const float2* pw = (const float2*)(weight + (size_t)lab * FEAT);
  float2 x = px[tid], w = pw[tid];
  float dot = block_reduce_sum(x.x * w.x + x.y * w.y, sbuf);
  float sx = block_reduce_sum(x.x * x.x + x.y * x.y, sbuf);
  float sw = block_reduce_sum(w.x * w.x + w.y * w.y, sbuf);

  // lse: plain sum of per-chunk exp-sums (fixed max = S)
  const float* p = partials + (size_t)r * NCHUNK;
  float l = 0.f;
  for (int i = tid; i < NCHUNK; i += 256) l += p[i];
  float lt = block_reduce_sum(l, sbuf);

  if (tid == 0) {
    float lse = SCALE_S + logf(lt);
    float tgt = outs[(size_t)r * NCLS + lab];
    atomicAdd(out0, (lse - tgt) * (1.0f / BATCH));

    float inv = 1.0f / (fmaxf(sqrtf(sx), 1e-12f) * fmaxf(sqrtf(sw), 1e-12f));
    float ci = fminf(fmaxf(dot * inv, -1.0f + 1e-6f), 1.0f - 1e-6f);
    float th = acosf(ci);
    float t2 = th + MARGIN;
    float co = (t2 < PI_F) ? cosf(t2) : (ci - MM_CONST);
    tdst[r] = ci;
    tdst[BATCH + r] = th;
    tdst[2 * BATCH + r] = co;
  }
}

extern "C" void kernel_launch(void* const* d_in, const int* in_sizes, int n_in,
                              void* d_out, int out_size, void* d_ws, size_t ws_size,
                              hipStream_t stream) {
  const float* inputs = (const float*)d_in[0];
  const int* labels = (const int*)d_in[1];
  const float* weight = (const float*)d_in[2];
  float* out = (float*)d_out;
  float* outs = out + 1;                                // [512][100000]
  float* tdst = out + 1 + (size_t)BATCH * NCLS;         // 3 x [512]

  // workspace layout
  char* ws = (char*)d_ws;
  u16* wsA = (u16*)ws;                                  // 512*512*2      = 524288 B
  u16* wsB = (u16*)(ws + 524288);                       // 100000*512*2   = 102400000 B
  float* partials = (float*)(ws + 524288 + 102400000);  // 512*1564*4     = 3203072 B

  norm_all_kernel<<<2048, 256, 0, stream>>>(inputs, weight, wsA, wsB, out);
  gemm_kernel<<<NBLK, 256, 0, stream>>>(wsA, wsB, labels, outs, partials);
  combine_kernel<<<BATCH, 256, 0, stream>>>(partials, outs, labels, inputs, weight, out, tdst);
}

// Round 5
// 527.269 us; speedup vs baseline: 1.0686x; 1.0686x over previous
//
#include <hip/hip_runtime.h>
#include <stdint.h>

#define BATCH 512
#define FEAT 512
#define NCLS 100000
#define BM 128                // A-rows per block
#define BN 64                 // B-rows (output cols) per block; whole K resident in LDS
#define NBN 1563              // ceil(100000/64)
#define NBLK (NBN * 4)        // 6252 blocks, bm-fastest
#define NCHUNK NBN            // one softmax partial per (row, 64-col block)
#define SCALE_S 32.0f
#define MARGIN 0.5f
#define MM_CONST 0.23971276930210156f  // 0.5*sin(pi-0.5)
#define PI_F 3.14159265358979f

typedef unsigned int u32;
typedef unsigned short u16;
typedef __bf16 bf16x8 __attribute__((ext_vector_type(8)));
typedef float f32x4 __attribute__((ext_vector_type(4)));

__device__ __forceinline__ u16 f2bf(float f) {
  u32 u = __float_as_uint(f);
  u += 0x7fffu + ((u >> 16) & 1u);
  return (u16)(u >> 16);
}

__device__ __forceinline__ void async_copy16(const void* g, void* l) {
  __builtin_amdgcn_global_load_lds((const __attribute__((address_space(1))) u32*)g,
                                   (__attribute__((address_space(3))) u32*)l,
                                   16, 0, 0);
}

__device__ __forceinline__ float block_reduce_sum(float v, float* sbuf) {
  for (int off = 1; off < 64; off <<= 1) v += __shfl_xor(v, off, 64);
  int wid = threadIdx.x >> 6, lane = threadIdx.x & 63;
  __syncthreads();
  if (lane == 0) sbuf[wid] = v;
  __syncthreads();
  return sbuf[0] + sbuf[1] + sbuf[2] + sbuf[3];
}

// Fused L2-normalize of inputs (BATCH rows) and weight (NCLS rows), f32 -> bf16.
// One wave per row, grid-stride; no LDS, no barriers; float4 loads, ushort4 stores.
// Also zeroes out[0] (loss accumulator used by combine_kernel's atomicAdd).
__global__ __launch_bounds__(256) void norm_all_kernel(const float* __restrict__ inputs,
                                                       const float* __restrict__ weight,
                                                       u16* __restrict__ dstA,
                                                       u16* __restrict__ dstB,
                                                       float* __restrict__ out0) {
  if (blockIdx.x == 0 && threadIdx.x == 0) out0[0] = 0.0f;
  const int lane = threadIdx.x & 63;
  const int gw = (blockIdx.x * 256 + threadIdx.x) >> 6;  // global wave id
  const int nw = gridDim.x * 4;                          // total waves
  for (int row = gw; row < BATCH + NCLS; row += nw) {
    const float* src;
    u16* dst;
    if (row < BATCH) {
      src = inputs + (size_t)row * FEAT;
      dst = dstA + (size_t)row * FEAT;
    } else {
      src = weight + (size_t)(row - BATCH) * FEAT;
      dst = dstB + (size_t)(row - BATCH) * FEAT;
    }
    const float4* p4 = (const float4*)src;
    float4 a = p4[lane];        // elements 4*lane .. 4*lane+3
    float4 b = p4[lane + 64];   // elements 256+4*lane ..
    float ss = a.x * a.x + a.y * a.y + a.z * a.z + a.w * a.w +
               b.x * b.x + b.y * b.y + b.z * b.z + b.w * b.w;
#pragma unroll
    for (int off = 1; off < 64; off <<= 1) ss += __shfl_xor(ss, off, 64);
    float inv = 1.0f / fmaxf(sqrtf(ss), 1e-12f);
    ushort4 oa, ob;
    oa.x = f2bf(a.x * inv); oa.y = f2bf(a.y * inv);
    oa.z = f2bf(a.z * inv); oa.w = f2bf(a.w * inv);
    ob.x = f2bf(b.x * inv); ob.y = f2bf(b.y * inv);
    ob.z = f2bf(b.z * inv); ob.w = f2bf(b.w * inv);
    ((ushort4*)dst)[lane] = oa;
    ((ushort4*)dst)[lane + 64] = ob;
  }
}

// C[512 x 100000] = Ahat @ Bhat^T (bf16 MFMA), fused clip/margin/scale epilogue,
// writes outs and per-(row, 64-col block) softmax partial sums with FIXED
// max = S (logits are analytically <= S): partial = sum exp(v - S).
// v4 structure (barrier-free K-loop):
//  - whole-K B-panel (64 rows x 512 cols bf16 = 64 KB) staged ONCE into LDS
//    via global_load_lds; one vmcnt(8)+s_barrier; then the K-loop has ZERO
//    barriers and ZERO staging - LDS is read-only.
//  - A fragments register-triple-buffered, prefetched 2 K-steps ahead direct
//    from global (A is 512 KB, L2-hot on every XCD).
//  - grid 1563 bn x 4 bm, bm-fastest; m204 bijective XCD chunking keeps the
//    4 bm-sharers of each B-panel temporally adjacent on one XCD's L2.
//  - plain (L2) C-stores: nontemporal doubled HBM write traffic (r3 ERRATA).
__global__ __launch_bounds__(256, 2) void gemm_kernel(const u16* __restrict__ A,
                                                      const u16* __restrict__ B,
                                                      const int* __restrict__ labels,
                                                      float* __restrict__ outs,
                                                      float* __restrict__ partials) {
  __shared__ __align__(16) u16 sB[BN * FEAT];  // 65536 B

  const int tid = threadIdx.x;
  const int lane = tid & 63;
  const int w = tid >> 6;            // wave id 0..3; wave owns rows w*32..w*32+31
  const int quad = lane >> 4, l15 = lane & 15;

  // m204 bijective XCD chunking (6252 = 8*781 + 4): XCD x gets a contiguous
  // L-range; consecutive L share bn (bm-fastest) -> B-panel L2 reuse.
  const int o = blockIdx.x;
  const int xcd = o & 7, slot = o >> 3;
  const int q = NBLK / 8, rr = NBLK % 8;  // 781, 4
  const int L = (xcd < rr ? xcd * (q + 1) : rr * (q + 1) + (xcd - rr) * q) + slot;
  const int bn = L >> 2, bm = L & 3;

  // ---- stage whole-K B panel: LDS 16B-block idx holds (row=idx>>6,
  // colblock=(idx&56)|((idx&7)^(row&7))) -- XOR swizzle for conflict-free
  // ds_read_b128 (16 lanes read 16 rows at same colblock).
#pragma unroll
  for (int p = 0; p < 16; ++p) {
    int idx = p * 256 + tid;
    int r = idx >> 6, c = idx & 63;
    int cg = (c & 56) | ((c & 7) ^ (r & 7));
    int brow = bn * BN + r;
    if (brow >= NCLS) brow = NCLS - 1;  // clamp; masked in epilogue
    async_copy16(B + (size_t)brow * FEAT + cg * 8, (u16*)sB + (size_t)idx * 8);
  }
  __builtin_amdgcn_sched_barrier(0);  // staging ops stay oldest in vmcnt queue

  // A fragment base: global row = bm*128 + w*32 + mi*16 + l15
  const u16* gA = A + (size_t)(bm * BM + w * 32 + l15) * FEAT;

  bf16x8 a0[2][2], a1[2][2], a2[2][2];

#define LOAD_A(AR, KT)                                                       \
  do {                                                                       \
    _Pragma("unroll") for (int mi = 0; mi < 2; ++mi)                         \
        _Pragma("unroll") for (int ks = 0; ks < 2; ++ks)                     \
            AR[mi][ks] = *(const bf16x8*)(gA + (size_t)mi * 16 * FEAT +      \
                                          (KT)*64 + (ks * 4 + quad) * 8);    \
  } while (0)

  LOAD_A(a0, 0);
  LOAD_A(a1, 1);
  __builtin_amdgcn_sched_barrier(0);
  // outstanding: 16 staging (oldest) + 8 A-loads; retire exactly the staging.
  asm volatile("s_waitcnt vmcnt(8)" ::: "memory");
  asm volatile("s_barrier" ::: "memory");  // all waves' panel DMA landed
  __builtin_amdgcn_sched_barrier(0);

  f32x4 acc[2][4] = {};

#define COMPUTE(AR, KT)                                                      \
  do {                                                                       \
    _Pragma("unroll") for (int ks = 0; ks < 2; ++ks) {                       \
      int j0 = ks * 4 + quad;                                                \
      bf16x8 bF[4];                                                          \
      _Pragma("unroll") for (int ni = 0; ni < 4; ++ni) {                     \
        int r = ni * 16 + l15;                                               \
        bF[ni] = *(const bf16x8*)&sB[(r * 64 + (KT)*8 + (j0 ^ (r & 7))) * 8];\
      }                                                                      \
      _Pragma("unroll") for (int mi = 0; mi < 2; ++mi)                       \
          _Pragma("unroll") for (int ni = 0; ni < 4; ++ni)                   \
              acc[mi][ni] = __builtin_amdgcn_mfma_f32_16x16x32_bf16(         \
                  AR[mi][ks], bF[ni], acc[mi][ni], 0, 0, 0);                 \
    }                                                                        \
  } while (0)

  // Barrier-free K-loop: prefetch A(t+2), compute t. Compiler emits the
  // minimal vmcnt for the A-regs (steady state: 8 outstanding -> vmcnt(8)).
  LOAD_A(a2, 2); __builtin_amdgcn_sched_barrier(0); COMPUTE(a0, 0);
  LOAD_A(a0, 3); __builtin_amdgcn_sched_barrier(0); COMPUTE(a1, 1);
  LOAD_A(a1, 4); __builtin_amdgcn_sched_barrier(0); COMPUTE(a2, 2);
  LOAD_A(a2, 5); __builtin_amdgcn_sched_barrier(0); COMPUTE(a0, 3);
  LOAD_A(a0, 6); __builtin_amdgcn_sched_barrier(0); COMPUTE(a1, 4);
  LOAD_A(a1, 7); __builtin_amdgcn_sched_barrier(0); COMPUTE(a2, 5);
  COMPUTE(a0, 6);
  COMPUTE(a1, 7);

#undef LOAD_A
#undef COMPUTE

  // epilogue: clip, margin at label col, scale, store (through L2), partial
  // exp-sums with FIXED max = SCALE_S.
#pragma unroll
  for (int mi = 0; mi < 2; ++mi) {
#pragma unroll
    for (int reg = 0; reg < 4; ++reg) {
      int rloc = w * 32 + mi * 16 + quad * 4 + reg;
      int rg = bm * BM + rloc;
      int lab = labels[rg];  // 512-int array, L1-hot broadcast
      float rsum = 0.f;
#pragma unroll
      for (int ni = 0; ni < 4; ++ni) {
        int cg = bn * BN + ni * 16 + l15;
        float v = acc[mi][ni][reg];
        v = fminf(fmaxf(v, -1.0f + 1e-6f), 1.0f - 1e-6f);
        if (cg == lab) {  // cos(arccos(x))==x elsewhere; only label col needs transcendentals
          float th = acosf(v) + MARGIN;
          v = (th < PI_F) ? cosf(th) : (v - MM_CONST);
        }
        v *= SCALE_S;
        if (cg < NCLS) {
          outs[(size_t)rg * NCLS + cg] = v;
          rsum += __expf(v - SCALE_S);
        }
      }
#pragma unroll
      for (int off = 1; off < 16; off <<= 1) rsum += __shfl_xor(rsum, off, 64);
      if (l15 == 0) partials[(size_t)rg * NCHUNK + bn] = rsum;
    }
  }
}

// per-row r: (a) sum NCHUNK partial exp-sums -> lse = S + log(sum), accumulate
// mean loss into out[0] via atomicAdd; (b) exact f32 recompute of
// target_cos_in / target_theta_in / target_cos_out.
__global__ __launch_bounds__(256) void combine_kernel(const float* __restrict__ partials,
                                                      const float* __restrict__ outs,
                                                      const int* __restrict__ labels,
                                                      const float* __restrict__ inputs,
                                                      const float* __restrict__ weight,
                                                      float* __restrict__ out0,
                                                      float* __restrict__ tdst) {
  __shared__ float sbuf[4];
  int r = blockIdx.x, tid = threadIdx.x;
  int lab = labels[r];

  // targets: three dot/norm reductions over the full 512-dim row (f32 exact)
  const float2* px = (const float2*)(inputs + (size_t)r * FEAT);
  const float2* pw = (const float2*)(weight + (size_t)lab * FEAT);
  float2 x = px[tid], w = pw[tid];
  float dot = block_reduce_sum(x.x * w.x + x.y * w.y, sbuf);
  float sx = block_reduce_sum(x.x * x.x + x.y * x.y, sbuf);
  float sw = block_reduce_sum(w.x * w.x + w.y * w.y, sbuf);

  // lse: plain sum of per-chunk exp-sums (fixed max = S)
  const float* p = partials + (size_t)r * NCHUNK;
  float l = 0.f;
  for (int i = tid; i < NCHUNK; i += 256) l += p[i];
  float lt = block_reduce_sum(l, sbuf);

  if (tid == 0) {
    float lse = SCALE_S + logf(lt);
    float tgt = outs[(size_t)r * NCLS + lab];
    atomicAdd(out0, (lse - tgt) * (1.0f / BATCH));

    float inv = 1.0f / (fmaxf(sqrtf(sx), 1e-12f) * fmaxf(sqrtf(sw), 1e-12f));
    float ci = fminf(fmaxf(dot * inv, -1.0f + 1e-6f), 1.0f - 1e-6f);
    float th = acosf(ci);
    float t2 = th + MARGIN;
    float co = (t2 < PI_F) ? cosf(t2) : (ci - MM_CONST);
    tdst[r] = ci;
    tdst[BATCH + r] = th;
    tdst[2 * BATCH + r] = co;
  }
}

extern "C" void kernel_launch(void* const* d_in, const int* in_sizes, int n_in,
                              void* d_out, int out_size, void* d_ws, size_t ws_size,
                              hipStream_t stream) {
  const float* inputs = (const float*)d_in[0];
  const int* labels = (const int*)d_in[1];
  const float* weight = (const float*)d_in[2];
  float* out = (float*)d_out;
  float* outs = out + 1;                                // [512][100000]
  float* tdst = out + 1 + (size_t)BATCH * NCLS;         // 3 x [512]

  // workspace layout
  char* ws = (char*)d_ws;
  u16* wsA = (u16*)ws;                                  // 512*512*2      = 524288 B
  u16* wsB = (u16*)(ws + 524288);                       // 100000*512*2   = 102400000 B
  float* partials = (float*)(ws + 524288 + 102400000);  // 512*1563*4     = 3201024 B

  norm_all_kernel<<<2048, 256, 0, stream>>>(inputs, weight, wsA, wsB, out);
  gemm_kernel<<<NBLK, 256, 0, stream>>>(wsA, wsB, labels, outs, partials);
  combine_kernel<<<BATCH, 256, 0, stream>>>(partials, outs, labels, inputs, weight, out, tdst);
}